// Round 2
// baseline (353.703 us; speedup 1.0000x reference)
//
#include <hip/hip_runtime.h>
#include <hip/hip_bf16.h>
#include <math.h>

// Caffe-style RPN proposal layer on gfx950.
// scores (1,64,64,18) f32 + deltas (1,64,64,36) f32 -> (300,4) f32.
// Pipeline: decode+hist -> radix-select+compact+LDS-sort+gather (1 block)
//           -> triangular IoU bitmask -> chunked greedy scan (1 wave) -> write.

#define NPROP   36864
#define TOPN    6000
#define POSTN   300
#define NWORDS  94          // ceil(6000/64)
#define SBUF_N  8192        // compacted sort size (64 KB LDS)

typedef unsigned long long u64;

// classic 9 anchors for base=16, ratios {0.5,1,2}, scales {8,16,32}
__constant__ float ANCH[9][4] = {
    {-84.f,  -40.f,  99.f,  55.f},
    {-176.f, -88.f,  191.f, 103.f},
    {-360.f, -184.f, 375.f, 199.f},
    {-56.f,  -56.f,  71.f,  71.f},
    {-120.f, -120.f, 135.f, 135.f},
    {-248.f, -248.f, 263.f, 263.f},
    {-36.f,  -80.f,  51.f,  95.f},
    {-80.f,  -168.f, 95.f,  183.f},
    {-168.f, -344.f, 183.f, 359.f},
};

// ---------- decode + sortable key + global top-byte histogram ----------
__global__ __launch_bounds__(256) void decode_kernel(
        const float* __restrict__ scores,
        const float* __restrict__ deltas,
        float4* __restrict__ boxes,
        u64* __restrict__ keys,
        unsigned* __restrict__ uhigh,
        unsigned* __restrict__ ghist) {
    __shared__ unsigned h[256];
    int t = threadIdx.x;
    if (t < 256) h[t] = 0;
    __syncthreads();

    int i = blockIdx.x * 256 + t;   // exactly NPROP threads
    int a   = i % 9;
    int pos = i / 9;
    int wx = pos & 63, hy = pos >> 6;
    float sx = (float)(wx * 16), sy = (float)(hy * 16);

    float ax1 = ANCH[a][0] + sx, ay1 = ANCH[a][1] + sy;
    float ax2 = ANCH[a][2] + sx, ay2 = ANCH[a][3] + sy;
    float aw  = ax2 - ax1 + 1.0f;
    float ah  = ay2 - ay1 + 1.0f;
    float acx = ax1 + 0.5f * aw;
    float acy = ay1 + 0.5f * ah;

    const float* d = deltas + ((size_t)pos * 36 + a * 4);
    float dx = d[0], dy = d[1], dw = d[2], dh = d[3];
    float fg = scores[(size_t)pos * 18 + 9 + a];

    // match unfused numpy rounding: block FMA contraction
    float pcx = __fadd_rn(__fmul_rn(dx, aw), acx);
    float pcy = __fadd_rn(__fmul_rn(dy, ah), acy);
    float pw  = __fmul_rn(expf(dw), aw);
    float ph  = __fmul_rn(expf(dh), ah);
    float hx  = __fmul_rn(0.5f, pw);
    float hv  = __fmul_rn(0.5f, ph);

    float x1 = fminf(fmaxf(__fsub_rn(pcx, hx), 0.0f), 1023.0f);
    float y1 = fminf(fmaxf(__fsub_rn(pcy, hv), 0.0f), 1023.0f);
    float x2 = fminf(fmaxf(__fadd_rn(pcx, hx), 0.0f), 1023.0f);
    float y2 = fminf(fmaxf(__fadd_rn(pcy, hv), 0.0f), 1023.0f);

    float bw = __fadd_rn(__fsub_rn(x2, x1), 1.0f);
    float bh = __fadd_rn(__fsub_rn(y2, y1), 1.0f);
    bool valid = (bw >= 16.0f) && (bh >= 16.0f);
    float sc = valid ? fg : -__builtin_huge_valf();

    boxes[i] = make_float4(x1, y1, x2, y2);

    unsigned u = __float_as_uint(sc);
    u = (u & 0x80000000u) ? ~u : (u | 0x80000000u);   // sortable: bigger = better
    uhigh[i] = u;
    keys[i]  = ((u64)u << 32) | (u64)(0xFFFFFFFFu - (unsigned)i); // tie: lower idx

    atomicAdd(&h[u >> 24], 1u);
    __syncthreads();
    if (t < 256 && h[t]) atomicAdd(&ghist[t], h[t]);
}

// ---------- radix-select threshold, compact, LDS bitonic sort, gather ----------
__global__ __launch_bounds__(1024) void topk_sort(
        const u64* __restrict__ keys,
        const unsigned* __restrict__ uhigh,
        const float4* __restrict__ boxes,
        const unsigned* __restrict__ ghist,
        float4* __restrict__ topb,
        float* __restrict__ areas,
        unsigned* __restrict__ topu) {
    __shared__ u64 sbuf[SBUF_N];            // 64 KB
    __shared__ unsigned hist[256];
    __shared__ unsigned sel1, sel2, sel3, need2, need3, scnt;
    int t = threadIdx.x;

    // ---- level 1: from the grid-wide histogram
    if (t == 0) {
        unsigned acc = 0; int b = 255;
        for (;; --b) { acc += ghist[b]; if (acc >= TOPN || b == 0) break; }
        sel1  = (unsigned)b;
        need2 = TOPN - (acc - ghist[b]);    // still needed from bucket b
        scnt  = 0;
    }
    if (t < 256) hist[t] = 0;
    __syncthreads();
    unsigned b1 = sel1;

    // ---- level 2: bits [23:16] among bucket b1
    for (int i = t; i < NPROP; i += 1024) {
        unsigned u = uhigh[i];
        if ((u >> 24) == b1) atomicAdd(&hist[(u >> 16) & 0xFFu], 1u);
    }
    __syncthreads();
    if (t == 0) {
        unsigned nd = need2;
        unsigned acc = 0; int b = 255;
        for (;; --b) { acc += hist[b]; if (acc >= nd || b == 0) break; }
        sel2  = (unsigned)b;
        need3 = nd - (acc - hist[b]);
    }
    __syncthreads();
    if (t < 256) hist[t] = 0;
    __syncthreads();
    unsigned p2 = (b1 << 8) | sel2;

    // ---- level 3: bits [15:8] among prefix p2
    for (int i = t; i < NPROP; i += 1024) {
        unsigned u = uhigh[i];
        if ((u >> 16) == p2) atomicAdd(&hist[(u >> 8) & 0xFFu], 1u);
    }
    __syncthreads();
    if (t == 0) {
        unsigned nd = need3;
        unsigned acc = 0; int b = 255;
        for (;; --b) { acc += hist[b]; if (acc >= nd || b == 0) break; }
        sel3 = (unsigned)b;
    }
    __syncthreads();
    unsigned thr = (b1 << 24) | (sel2 << 16) | (sel3 << 8);

    // ---- compact all keys with high word >= thr (count in [TOPN, ~TOPN+eps])
    for (int i = t; i < NPROP; i += 1024) {
        if (uhigh[i] >= thr) {
            unsigned p = atomicAdd(&scnt, 1u);
            if (p < SBUF_N) sbuf[p] = keys[i];
        }
    }
    __syncthreads();
    unsigned n = scnt; if (n > SBUF_N) n = SBUF_N;
    for (int i = t; i < SBUF_N; i += 1024)
        if ((unsigned)i >= n) sbuf[i] = 0ULL;
    __syncthreads();

    // ---- bitonic sort SBUF_N keys descending
    for (int k = 2; k <= SBUF_N; k <<= 1) {
        for (int j = k >> 1; j >= 1; j >>= 1) {
            #pragma unroll
            for (int r = 0; r < SBUF_N / 2048; ++r) {
                int p  = t + (r << 10);
                int li = ((p & ~(j - 1)) << 1) | (p & (j - 1));
                int lj = li | j;
                u64 a = sbuf[li], b = sbuf[lj];
                bool desc = ((li & k) == 0);
                bool sw = desc ? (a < b) : (a > b);
                if (sw) { sbuf[li] = b; sbuf[lj] = a; }
            }
            __syncthreads();
        }
    }

    // ---- gather top-6000 boxes / areas / score-patterns
    for (int i = t; i < TOPN; i += 1024) {
        u64 key = sbuf[i];
        if (key == 0ULL) {      // padding (only if <6000 candidates ever)
            topb[i] = make_float4(0.f, 0.f, 0.f, 0.f);
            areas[i] = 1.f;
            topu[i] = 0x007FFFFFu;
            continue;
        }
        unsigned idx = 0xFFFFFFFFu - (unsigned)(key & 0xFFFFFFFFull);
        float4 b = boxes[idx];
        topb[i] = b;
        areas[i] = __fmul_rn(__fadd_rn(__fsub_rn(b.z, b.x), 1.0f),
                             __fadd_rn(__fsub_rn(b.w, b.y), 1.0f));
        topu[i] = (unsigned)(key >> 32);
    }
}

// ---------- NMS suppression bit-matrix (upper triangle only) ----------
__global__ void nms_mask(const float4* __restrict__ boxes,
                         const float* __restrict__ areas,
                         u64* __restrict__ mask) {
    int rb = blockIdx.x, cb = blockIdx.y;
    if (cb < rb) return;                       // j > i only
    __shared__ float4 cbx[64];
    __shared__ float  car[64];
    int tid = threadIdx.x;
    int j0 = cb * 64;
    if (j0 + tid < TOPN) { cbx[tid] = boxes[j0 + tid]; car[tid] = areas[j0 + tid]; }
    __syncthreads();
    int i = rb * 64 + tid;
    if (i >= TOPN) return;
    float4 bi = boxes[i];
    float  ai = areas[i];
    u64 bits = 0ULL;
    int jmax = min(64, TOPN - j0);
    for (int jj = 0; jj < jmax; ++jj) {
        int j = j0 + jj;
        if (j <= i) continue;
        float4 bj = cbx[jj];
        float xx1 = fmaxf(bi.x, bj.x);
        float yy1 = fmaxf(bi.y, bj.y);
        float xx2 = fminf(bi.z, bj.z);
        float yy2 = fminf(bi.w, bj.w);
        float w = fmaxf(__fadd_rn(__fsub_rn(xx2, xx1), 1.0f), 0.0f);
        float h = fmaxf(__fadd_rn(__fsub_rn(yy2, yy1), 1.0f), 0.0f);
        float inter = __fmul_rn(w, h);
        float denom = __fsub_rn(__fadd_rn(ai, car[jj]), inter);
        float iou = inter / denom;
        if (iou > 0.5f) bits |= (1ULL << jj);
    }
    mask[(size_t)i * NWORDS + cb] = bits;
}

// ---------- chunked greedy scan: one wave ----------
// Removed-state distributed: lane l owns word l (boxes 64l..64l+63) in rem0
// and word 64+l in rem1. Per 64-box chunk: resolve greedily in-register
// (one ctz+shfl step per KEPT box), then bulk-OR kept rows into the state
// with parallel loads. -inf boxes suppress but are not recorded (ref applies
// isfinite AFTER nms).
__global__ void nms_seq(const unsigned* __restrict__ topu,
                        const u64* __restrict__ mask,
                        int* __restrict__ kept, int* __restrict__ count_out) {
    int lane = threadIdx.x;  // 0..63
    u64 rem0 = 0ULL, rem1 = 0ULL;
    int cnt = 0;

    // prefetch chunk 0 intra-chunk row word
    u64 self = mask[(size_t)lane * NWORDS + 0];

    for (int c = 0; c < NWORDS && cnt < POSTN; ++c) {
        int i0 = c * 64;
        int nbox = min(64, TOPN - i0);
        u64 selfmask = self;
        // prefetch next chunk's intra-chunk words (state-independent)
        if (c + 1 < NWORDS) {
            int i0n = (c + 1) * 64;
            self = (i0n + lane < TOPN)
                 ? mask[(size_t)(i0n + lane) * NWORDS + (c + 1)] : 0ULL;
        }

        // current removed word for this chunk
        u64 myword = (c < 64) ? rem0 : rem1;
        int owner  = (c < 64) ? c : (c - 64);
        u64 R = __shfl(myword, owner, 64);

        // finite flags for this chunk
        unsigned u = (i0 + lane < TOPN) ? topu[i0 + lane] : 0x007FFFFFu;
        u64 F = __ballot(u != 0x007FFFFFu);

        u64 validm = (nbox == 64) ? ~0ULL : ((1ULL << nbox) - 1ULL);
        u64 aliveC = (~R) & validm;
        u64 keptw = 0ULL;
        while (aliveC) {
            int ii = __builtin_ctzll(aliveC);        // lowest alive -> kept
            keptw |= (1ULL << ii);
            u64 row = __shfl(selfmask, ii, 64);      // its intra-chunk suppressions
            aliveC &= ~(1ULL << ii);
            aliveC &= ~row;
        }

        // record finite kept indices in rank order, capped at POSTN
        u64 kf = keptw & F;
        if (lane == 0) {
            u64 k2 = kf; int cc = cnt;
            while (k2 && cc < POSTN) {
                int ii = __builtin_ctzll(k2); k2 &= k2 - 1ULL;
                kept[cc++] = i0 + ii;
            }
        }
        cnt += __popcll(kf);
        if (cnt > POSTN) cnt = POSTN;

        // bulk-apply kept rows to future removed state (parallel across lanes,
        // independent loads across kept boxes)
        u64 kw = keptw;
        while (kw) {
            int ii = __builtin_ctzll(kw); kw &= kw - 1ULL;
            size_t base = (size_t)(i0 + ii) * NWORDS;
            rem0 |= mask[base + lane];
            if (64 + lane < NWORDS) rem1 |= mask[base + 64 + lane];
        }
    }
    if (lane == 0) *count_out = cnt;
}

__global__ void write_out(const float4* __restrict__ top,
                          const int* __restrict__ kept,
                          const int* __restrict__ count,
                          float* __restrict__ out) {
    int t = blockIdx.x * blockDim.x + threadIdx.x;
    if (t >= POSTN) return;
    int c = *count;
    float x = 0.f, y = 0.f, z = 0.f, w = 0.f;
    if (t < c) {
        float4 v = top[kept[t]];
        x = v.x / 1024.0f; y = v.y / 1024.0f; z = v.z / 1024.0f; w = v.w / 1024.0f;
    }
    out[t * 4 + 0] = x;
    out[t * 4 + 1] = y;
    out[t * 4 + 2] = z;
    out[t * 4 + 3] = w;
}

extern "C" void kernel_launch(void* const* d_in, const int* in_sizes, int n_in,
                              void* d_out, int out_size, void* d_ws, size_t ws_size,
                              hipStream_t stream) {
    const float* scores = (const float*)d_in[0];   // (1,64,64,18)
    const float* deltas = (const float*)d_in[1];   // (1,64,64,36)
    float* out = (float*)d_out;                    // 300*4

    char* w = (char*)d_ws;
    float4*   boxes = (float4*)(w);                          // 589824 B
    u64*      keys  = (u64*)(w + 589824);                    // 294912 B
    unsigned* uhigh = (unsigned*)(w + 884736);               // 147456 B
    float4*   topb  = (float4*)(w + 1032192);                // 96000 B
    float*    areas = (float*)(w + 1128192);                 // 24000 B
    unsigned* topu  = (unsigned*)(w + 1152192);              // 24000 B
    u64*      mask  = (u64*)(w + 1176192);                   // 4512000 B
    int*      kept  = (int*)(w + 5688192);                   // 1200 B
    int*      cnt   = (int*)(w + 5689392);                   // 4 B
    unsigned* ghist = (unsigned*)(w + 5689396);              // 1024 B

    hipMemsetAsync(ghist, 0, 256 * sizeof(unsigned), stream);
    decode_kernel<<<NPROP / 256, 256, 0, stream>>>(scores, deltas, boxes, keys, uhigh, ghist);
    topk_sort<<<1, 1024, 0, stream>>>(keys, uhigh, boxes, ghist, topb, areas, topu);
    nms_mask<<<dim3(NWORDS, NWORDS), 64, 0, stream>>>(topb, areas, mask);
    nms_seq<<<1, 64, 0, stream>>>(topu, mask, kept, cnt);
    write_out<<<1, 320, 0, stream>>>(topb, kept, cnt, out);
}